// Round 17
// baseline (1066.938 us; speedup 1.0000x reference)
//
#include <hip/hip_runtime.h>
#include <float.h>
#include <math.h>

#define B_ 8
#define N_ 1024
#define C_ 768
#define H_ 12
#define HD_ 64
#define BH_ (B_*H_)

typedef __attribute__((ext_vector_type(8))) short bf16x8;
typedef __attribute__((ext_vector_type(4))) float f32x4;

// ordered-uint pack: bigger key = (bigger value) or (equal value, smaller idx)
__device__ __forceinline__ unsigned long long makekey(float v, int idx) {
    unsigned int b = __float_as_uint(v);
    unsigned int o = (b & 0x80000000u) ? ~b : (b | 0x80000000u);
    return ((unsigned long long)o << 32) | (unsigned int)(1023 - idx);
}
__device__ __forceinline__ float keyval(unsigned long long k) {
    unsigned int ordv = (unsigned int)(k >> 32);
    unsigned int fb = (ordv & 0x80000000u) ? (ordv & 0x7FFFFFFFu) : ~ordv;
    return __uint_as_float(fb);
}
// RNE f32 -> bf16 (no NaN inputs here)
__device__ __forceinline__ unsigned short f2bf(float f) {
    unsigned int u = __float_as_uint(f);
    return (unsigned short)((u + 0x7FFFu + ((u >> 16) & 1u)) >> 16);
}

// ---------------- fp32 GEMM (Q,K selection path): C = A * W^T + bias ----------------
// Tile 64x128 (acc 4x8), 1536 blocks -> ~6 blocks/CU. Sequential in-order K chain per
// output element (np-matching, bit-identical). LDS double-buffered, XCD-swizzled.
// MODE 1: o/768==0 -> Q row-major [bh][n][64]; ==1 -> K TRANSPOSED [bh][d][n].
template<int MM, int NN, int KD, int MODE>
__global__ void __launch_bounds__(256, 6)
gemm_k(const float* __restrict__ A, const float* __restrict__ W,
       const float* __restrict__ bias, float* __restrict__ out)
{
    __shared__ float As[2][16][68];
    __shared__ float Bs[2][16][132];
    const int tid = threadIdx.x;
    constexpr int NBLK = NN / 128;
    constexpr int NWG = (MM / 64) * NBLK;           // multiple of 8
    const int eff = (blockIdx.x & 7) * (NWG / 8) + (blockIdx.x >> 3);  // bijective XCD swizzle
    const int bm = eff / NBLK;
    const int bn = eff % NBLK;
    const int m0 = bm * 64, n0 = bn * 128;
    const int ty = tid >> 4, tx = tid & 15;
    const int ar = tid >> 2;           // 0..63
    const int ac = (tid & 3) << 2;     // 0,4,8,12

    float acc[4][8];
#pragma unroll
    for (int i = 0; i < 4; ++i)
#pragma unroll
        for (int j = 0; j < 8; ++j) acc[i][j] = 0.f;

    const float* A0 = A + (size_t)(m0 + ar) * KD + ac;
    const float* W0 = W + (size_t)(n0 + ar) * KD + ac;
    const float* W1 = W + (size_t)(n0 + ar + 64) * KD + ac;

    float4 pa0 = *(const float4*)A0;
    float4 pb0 = *(const float4*)W0;
    float4 pb1 = *(const float4*)W1;

    // preamble: stage k0=0 into buffer 0
    As[0][ac+0][ar] = pa0.x; As[0][ac+1][ar] = pa0.y; As[0][ac+2][ar] = pa0.z; As[0][ac+3][ar] = pa0.w;
    Bs[0][ac+0][ar]    = pb0.x; Bs[0][ac+1][ar]    = pb0.y; Bs[0][ac+2][ar]    = pb0.z; Bs[0][ac+3][ar]    = pb0.w;
    Bs[0][ac+0][ar+64] = pb1.x; Bs[0][ac+1][ar+64] = pb1.y; Bs[0][ac+2][ar+64] = pb1.z; Bs[0][ac+3][ar+64] = pb1.w;
    __syncthreads();

    int cur = 0;
    for (int k0 = 0; k0 < KD; k0 += 16) {
        const bool more = (k0 + 16 < KD);
        if (more) {
            pa0 = *(const float4*)(A0 + k0 + 16);
            pb0 = *(const float4*)(W0 + k0 + 16);
            pb1 = *(const float4*)(W1 + k0 + 16);
        }
        const float (*Ac)[68]  = As[cur];
        const float (*Bc)[132] = Bs[cur];
#pragma unroll
        for (int kk = 0; kk < 16; ++kk) {
            float4 a0v = *(const float4*)&Ac[kk][ty * 4];
            float4 b0v = *(const float4*)&Bc[kk][tx * 4];
            float4 b1v = *(const float4*)&Bc[kk][64 + tx * 4];
            float av[4] = {a0v.x,a0v.y,a0v.z,a0v.w};
            float bv[8] = {b0v.x,b0v.y,b0v.z,b0v.w, b1v.x,b1v.y,b1v.z,b1v.w};
#pragma unroll
            for (int i = 0; i < 4; ++i)
#pragma unroll
                for (int j = 0; j < 8; ++j)
                    acc[i][j] = fmaf(av[i], bv[j], acc[i][j]);
        }
        if (more) {
            const int nxt = cur ^ 1;
            As[nxt][ac+0][ar] = pa0.x; As[nxt][ac+1][ar] = pa0.y; As[nxt][ac+2][ar] = pa0.z; As[nxt][ac+3][ar] = pa0.w;
            Bs[nxt][ac+0][ar]    = pb0.x; Bs[nxt][ac+1][ar]    = pb0.y; Bs[nxt][ac+2][ar]    = pb0.z; Bs[nxt][ac+3][ar]    = pb0.w;
            Bs[nxt][ac+0][ar+64] = pb1.x; Bs[nxt][ac+1][ar+64] = pb1.y; Bs[nxt][ac+2][ar+64] = pb1.z; Bs[nxt][ac+3][ar+64] = pb1.w;
            __syncthreads();
            cur = nxt;
        }
    }

#pragma unroll
    for (int i = 0; i < 4; ++i) {
        const int m = m0 + ty * 4 + i;
#pragma unroll
        for (int gj = 0; gj < 2; ++gj) {
            const int o = n0 + gj * 64 + tx * 4;
            const int aj = gj * 4;
            float4 bv4 = *(const float4*)(bias + o);
            float4 v;
            v.x = acc[i][aj+0] + bv4.x;
            v.y = acc[i][aj+1] + bv4.y;
            v.z = acc[i][aj+2] + bv4.z;
            v.w = acc[i][aj+3] + bv4.w;
            if (MODE == 0) {
                *(float4*)(out + (size_t)m * NN + o) = v;
            } else {
                const int which = o / 768;           // 0=Q, 1=K
                const int r = o - which * 768;
                const int hh = r >> 6;
                const int dd = r & 63;
                const int bh = (m >> 10) * H_ + hh;
                const int nn = m & 1023;
                if (which == 1) {
                    // K TRANSPOSED: [bh][d][n]
                    float* dst = out + (size_t)BH_ * N_ * HD_
                               + ((size_t)bh * HD_ + dd) * N_ + nn;
                    dst[0]      = v.x;
                    dst[N_]     = v.y;
                    dst[2 * N_] = v.z;
                    dst[3 * N_] = v.w;
                } else {
                    float* dst = out + ((size_t)bh * N_ + nn) * HD_ + dd;
                    *(float4*)dst = v;
                }
            }
        }
    }
}

// ---------------- bf16 MFMA GEMM (value path): C = A * W^T + bias ----------------
// Unchanged from r16 (verified): tile 128x128, BK=32, 4 waves, MFMA 16x16x32.
template<int MM, int NN, int MODE>
__global__ void __launch_bounds__(256)
gemm_bf_k(const float* __restrict__ A, const float* __restrict__ W,
          const float* __restrict__ bias, float* __restrict__ out)
{
    __shared__ unsigned short Asb[128][40];
    __shared__ unsigned short Bsb[128][40];
    const int tid = threadIdx.x;
    constexpr int NBLK = NN / 128;
    constexpr int NWG = (MM / 128) * NBLK;
    const int eff = (blockIdx.x & 7) * (NWG / 8) + (blockIdx.x >> 3);
    const int bm = eff / NBLK;
    const int bn = eff % NBLK;
    const int m0 = bm * 128, n0 = bn * 128;
    const int lane = tid & 63;
    const int w = tid >> 6;
    const int wm = (w >> 1) << 6;
    const int wn = (w & 1) << 6;

    f32x4 acc[4][4];
#pragma unroll
    for (int i = 0; i < 4; ++i)
#pragma unroll
        for (int j = 0; j < 4; ++j) acc[i][j] = (f32x4){0.f, 0.f, 0.f, 0.f};

    const int srow = tid >> 1;
    const int sks  = (tid & 1) << 4;
    const float* ga = A + (size_t)(m0 + srow) * 768 + sks;
    const float* gw = W + (size_t)(n0 + srow) * 768 + sks;

    for (int k0 = 0; k0 < 768; k0 += 32) {
        __syncthreads();
        {
            float4 f0 = *(const float4*)(ga + k0 + 0);
            float4 f1 = *(const float4*)(ga + k0 + 4);
            float4 f2 = *(const float4*)(ga + k0 + 8);
            float4 f3 = *(const float4*)(ga + k0 + 12);
            unsigned short* d = &Asb[srow][sks];
            d[0]=f2bf(f0.x);  d[1]=f2bf(f0.y);  d[2]=f2bf(f0.z);  d[3]=f2bf(f0.w);
            d[4]=f2bf(f1.x);  d[5]=f2bf(f1.y);  d[6]=f2bf(f1.z);  d[7]=f2bf(f1.w);
            d[8]=f2bf(f2.x);  d[9]=f2bf(f2.y);  d[10]=f2bf(f2.z); d[11]=f2bf(f2.w);
            d[12]=f2bf(f3.x); d[13]=f2bf(f3.y); d[14]=f2bf(f3.z); d[15]=f2bf(f3.w);
            f0 = *(const float4*)(gw + k0 + 0);
            f1 = *(const float4*)(gw + k0 + 4);
            f2 = *(const float4*)(gw + k0 + 8);
            f3 = *(const float4*)(gw + k0 + 12);
            unsigned short* e = &Bsb[srow][sks];
            e[0]=f2bf(f0.x);  e[1]=f2bf(f0.y);  e[2]=f2bf(f0.z);  e[3]=f2bf(f0.w);
            e[4]=f2bf(f1.x);  e[5]=f2bf(f1.y);  e[6]=f2bf(f1.z);  e[7]=f2bf(f1.w);
            e[8]=f2bf(f2.x);  e[9]=f2bf(f2.y);  e[10]=f2bf(f2.z); e[11]=f2bf(f2.w);
            e[12]=f2bf(f3.x); e[13]=f2bf(f3.y); e[14]=f2bf(f3.z); e[15]=f2bf(f3.w);
        }
        __syncthreads();

        bf16x8 af[4], bf[4];
        const int fr = lane & 15;
        const int fk = (lane >> 4) << 3;
#pragma unroll
        for (int fi = 0; fi < 4; ++fi)
            af[fi] = *(const bf16x8*)&Asb[wm + (fi << 4) + fr][fk];
#pragma unroll
        for (int fj = 0; fj < 4; ++fj)
            bf[fj] = *(const bf16x8*)&Bsb[wn + (fj << 4) + fr][fk];
#pragma unroll
        for (int fi = 0; fi < 4; ++fi)
#pragma unroll
            for (int fj = 0; fj < 4; ++fj)
                acc[fi][fj] = __builtin_amdgcn_mfma_f32_16x16x32_bf16(af[fi], bf[fj], acc[fi][fj], 0, 0, 0);
    }

    const int cr = (lane >> 4) << 2;
    const int cc = lane & 15;
#pragma unroll
    for (int fj = 0; fj < 4; ++fj) {
        const int col = n0 + wn + (fj << 4) + cc;
        const float bb = bias[col];
#pragma unroll
        for (int fi = 0; fi < 4; ++fi) {
#pragma unroll
            for (int j = 0; j < 4; ++j) {
                const int row = m0 + wm + (fi << 4) + cr + j;
                const float val = acc[fi][fj][j] + bb;
                if (MODE == 0) {
                    out[(size_t)row * NN + col] = val;
                } else {
                    const int hh = col >> 6;
                    const int dd = col & 63;
                    const int bh = (row >> 10) * H_ + hh;
                    const int nn = row & 1023;
                    out[((size_t)bh * N_ + nn) * HD_ + dd] = val;
                }
            }
        }
    }
}

// ------- fused scores + top-16 (tiered rank-count, u64 keys) -> compact winner list -------
// grid: BH_*128 = 12288 blocks (XCD-swizzled), 256 threads (4 waves). Each block: 8 q-rows.
// Wave w = col-group (cols w*256..+255); thread tile 8 rows x 4 cols (R_w=8).
__global__ void __launch_bounds__(256, 5)
attn_k(const float* __restrict__ Qg, const float* __restrict__ Ktg,
       uint2* __restrict__ wlist)
{
    __shared__ float Qs[64][8];                     // 2 KB   [d][q]
    __shared__ float qm[8][64];                     // 2 KB   quad maxes per row (4 cgs x 16)
    __shared__ unsigned long long kbuf[8][384];     // 24 KB  survivor keys (4 segs x 96 per row)
    __shared__ int cnt[8][4];                       // 128 B
    __shared__ uint2 w16s[8][16];                   // 1 KB   winners by rank (idx, wgt-bits)

    const int tid = threadIdx.x;
    const int lane = tid & 63;
    const int w = tid >> 6;                         // 0..3 col-group
    // XCD-aware BIJECTIVE swizzle: 12288 blocks = 8 XCDs x 1536 chunks
    const int eff = (blockIdx.x & 7) * 1536 + (blockIdx.x >> 3);
    const int bh = eff >> 7;
    const int qt = eff & 127;
    const int q0 = qt << 3;
    const size_t kvbase = (size_t)bh * (N_ * HD_);

    if (tid < 128) {   // stage Q transposed: Qs[d][q]
        int q = tid >> 4;                           // 0..7
        int d4 = (tid & 15) << 2;
        float4 v = *(const float4*)(Qg + kvbase + (size_t)(q0 + q) * HD_ + d4);
        Qs[d4+0][q] = v.x; Qs[d4+1][q] = v.y; Qs[d4+2][q] = v.z; Qs[d4+3][q] = v.w;
    }
    __syncthreads();

    float acc[8][4];
#pragma unroll
    for (int r = 0; r < 8; ++r)
#pragma unroll
        for (int u = 0; u < 4; ++u) acc[r][u] = 0.f;

    const int jb = (w << 8) + (lane << 2);
    const float* kcol = Ktg + kvbase + jb;          // K^T [d][j], + d*1024

    // sequential d = 0..63 in-order fp32 FMA accumulation (np-matching)
#pragma unroll 8
    for (int d = 0; d < 64; ++d) {
        float4 kvv = *(const float4*)(kcol + (d << 10));
        float4 qa = *(const float4*)&Qs[d][0];
        float4 qb = *(const float4*)&Qs[d][4];
        float qv[8] = {qa.x, qa.y, qa.z, qa.w, qb.x, qb.y, qb.z, qb.w};
#pragma unroll
        for (int r = 0; r < 8; ++r) {
            acc[r][0] = fmaf(qv[r], kvv.x, acc[r][0]);
            acc[r][1] = fmaf(qv[r], kvv.y, acc[r][1]);
            acc[r][2] = fmaf(qv[r], kvv.z, acc[r][2]);
            acc[r][3] = fmaf(qv[r], kvv.w, acc[r][3]);
        }
    }

    // scale (exact pow2 -> ordering-safe)
#pragma unroll
    for (int r = 0; r < 8; ++r)
#pragma unroll
        for (int u = 0; u < 4; ++u) acc[r][u] *= 0.125f;

    // (a) per-row quad maxes (quad of 4 lanes = 16 cols)
#pragma unroll
    for (int rr = 0; rr < 8; ++rr) {
        float lm = fmaxf(fmaxf(acc[rr][0], acc[rr][1]), fmaxf(acc[rr][2], acc[rr][3]));
        lm = fmaxf(lm, __shfl_xor(lm, 1));
        lm = fmaxf(lm, __shfl_xor(lm, 2));
        if ((lane & 3) == 0) qm[rr][(w << 4) + (lane >> 2)] = lm;
    }
    __syncthreads();

    // (c) threshold T = min of 16 disjoint supergroup-maxes; compact survivors (cap 96/seg)
#pragma unroll
    for (int rr = 0; rr < 8; ++rr) {
        const int g = lane & 15;
        float sg = fmaxf(fmaxf(qm[rr][g], qm[rr][16 + g]),
                         fmaxf(qm[rr][32 + g], qm[rr][48 + g]));
        sg = fminf(sg, __shfl_xor(sg, 1));
        sg = fminf(sg, __shfl_xor(sg, 2));
        sg = fminf(sg, __shfl_xor(sg, 4));
        sg = fminf(sg, __shfl_xor(sg, 8));
        const float T = sg;
        int base = 0;
        unsigned long long lowmask = (lane == 0) ? 0ull : ((1ull << lane) - 1ull);
#pragma unroll
        for (int u = 0; u < 4; ++u) {
            bool f = acc[rr][u] >= T;
            unsigned long long m = __ballot(f);
            int pos = base + __popcll(m & lowmask);
            if (f && pos < 96) kbuf[rr][w * 96 + pos] = makekey(acc[rr][u], jb + u);
            base += __popcll(m);
        }
        if (lane == 0) cnt[rr][w] = base < 96 ? base : 96;
    }
    __syncthreads();

    // (e) selection: wave w owns rows 2w, 2w+1; tiered rank-count -> wlist
#pragma unroll 1
    for (int rr2 = 0; rr2 < 2; ++rr2) {
        const int r = (w << 1) | rr2;
        const int c0n = cnt[r][0], c1n = cnt[r][1], c2n = cnt[r][2], c3n = cnt[r][3];
        const int pfx1 = c0n, pfx2 = c0n + c1n, pfx3 = c0n + c1n + c2n;
        const int Ctot = pfx3 + c3n;             // 16..384

        auto mapk = [&](int p) -> unsigned long long {
            if (p >= Ctot) return 0ull;
            int wseg, pos;
            if (p < pfx1)      { wseg = 0; pos = p; }
            else if (p < pfx2) { wseg = 1; pos = p - pfx1; }
            else if (p < pfx3) { wseg = 2; pos = p - pfx2; }
            else               { wseg = 3; pos = p - pfx3; }
            return kbuf[r][wseg * 96 + pos];
        };

        if (Ctot <= 128) {
            unsigned long long kk0 = mapk(lane);
            unsigned long long kk1 = mapk(lane + 64);
            int n0 = 0, n1 = 0;
#pragma unroll 1
            for (int seg = 0; seg < 4; ++seg) {
                const int cn = cnt[r][seg];
                const unsigned long long* sp = &kbuf[r][seg * 96];
#pragma unroll 4
                for (int p = 0; p < cn; ++p) {
                    unsigned long long kp = sp[p];   // broadcast read
                    n0 += (kp > kk0); n1 += (kp > kk1);
                }
            }
            float v0 = keyval(kk0), v1 = keyval(kk1);
            float mc = -FLT_MAX;
            if (n0 == 0) mc = v0;
            if (n1 == 0) mc = v1;
#pragma unroll
            for (int off = 1; off < 64; off <<= 1) mc = fmaxf(mc, __shfl_xor(mc, off));
            float e0 = (n0 < 16) ? expf(v0 - mc) : 0.f;
            float e1 = (n1 < 16) ? expf(v1 - mc) : 0.f;
            float es = e0 + e1;
#pragma unroll
            for (int off = 1; off < 64; off <<= 1) es += __shfl_xor(es, off);
            if (n0 < 16) w16s[r][n0] = make_uint2(1023u - (unsigned)(kk0 & 0xFFFFFFFFull), __float_as_uint(e0 / es));
            if (n1 < 16) w16s[r][n1] = make_uint2(1023u - (unsigned)(kk1 & 0xFFFFFFFFull), __float_as_uint(e1 / es));
        } else {
            unsigned long long kk0 = mapk(lane);
            unsigned long long kk1 = mapk(lane + 64);
            unsigned long long kk2 = mapk(lane + 128);
            unsigned long long kk3 = mapk(lane + 192);
            unsigned long long kk4 = mapk(lane + 256);
            unsigned long long kk5 = mapk(lane + 320);
            int n0 = 0, n1 = 0, n2 = 0, n3 = 0, n4 = 0, n5 = 0;
#pragma unroll 1
            for (int seg = 0; seg < 4; ++seg) {
                const int cn = cnt[r][seg];
                const unsigned long long* sp = &kbuf[r][seg * 96];
#pragma unroll 2
                for (int p = 0; p < cn; ++p) {
                    unsigned long long kp = sp[p];
                    n0 += (kp > kk0); n1 += (kp > kk1); n2 += (kp > kk2);
                    n3 += (kp > kk3); n4 += (kp > kk4); n5 += (kp > kk5);
                }
            }
            float v0 = keyval(kk0), v1 = keyval(kk1), v2 = keyval(kk2);
            float v3 = keyval(kk3), v4 = keyval(kk4), v5 = keyval(kk5);
            float mc = -FLT_MAX;
            if (n0 == 0) mc = v0;
            if (n1 == 0) mc = v1;
            if (n2 == 0) mc = v2;
            if (n3 == 0) mc = v3;
            if (n4 == 0) mc = v4;
            if (n5 == 0) mc = v5;
#pragma unroll
            for (int off = 1; off < 64; off <<= 1) mc = fmaxf(mc, __shfl_xor(mc, off));
            float e0 = (n0 < 16) ? expf(v0 - mc) : 0.f;
            float e1 = (n1 < 16) ? expf(v1 - mc) : 0.f;
            float e2 = (n2 < 16) ? expf(v2 - mc) : 0.f;
            float e3 = (n3 < 16) ? expf(v3 - mc) : 0.f;
            float e4 = (n4 < 16) ? expf(v4 - mc) : 0.f;
            float e5 = (n5 < 16) ? expf(v5 - mc) : 0.f;
            float es = e0 + e1 + e2 + e3 + e4 + e5;
#pragma unroll
            for (int off = 1; off < 64; off <<= 1) es += __shfl_xor(es, off);
            if (n0 < 16) w16s[r][n0] = make_uint2(1023u - (unsigned)(kk0 & 0xFFFFFFFFull), __float_as_uint(e0 / es));
            if (n1 < 16) w16s[r][n1] = make_uint2(1023u - (unsigned)(kk1 & 0xFFFFFFFFull), __float_as_uint(e1 / es));
            if (n2 < 16) w16s[r][n2] = make_uint2(1023u - (unsigned)(kk2 & 0xFFFFFFFFull), __float_as_uint(e2 / es));
            if (n3 < 16) w16s[r][n3] = make_uint2(1023u - (unsigned)(kk3 & 0xFFFFFFFFull), __float_as_uint(e3 / es));
            if (n4 < 16) w16s[r][n4] = make_uint2(1023u - (unsigned)(kk4 & 0xFFFFFFFFull), __float_as_uint(e4 / es));
            if (n5 < 16) w16s[r][n5] = make_uint2(1023u - (unsigned)(kk5 & 0xFFFFFFFFull), __float_as_uint(e5 / es));
        }
        asm volatile("s_waitcnt lgkmcnt(0)" ::: "memory");   // in-wave LDS write->read ordering
        __builtin_amdgcn_sched_barrier(0);

        if (lane < 16)
            wlist[((size_t)bh * N_ + q0 + r) * 16 + lane] = w16s[r][lane];
    }
}

// ------- PV + aout + topk zero-fill/scatter (barrier-free, pure throughput) -------
__global__ void __launch_bounds__(256)
pv_scatter_k(const uint2* __restrict__ wlist, const float* __restrict__ Vg,
             float* __restrict__ topk, float* __restrict__ aout)
{
    const int tid = threadIdx.x;
    const int lane = tid & 63;
    const int row = (blockIdx.x << 2) + (tid >> 6);
    const size_t base = (size_t)row << 10;
    const int bh = row >> 10;
    const int n = row & 1023;
    const int b = bh / H_;
    const int h = bh - b * H_;

    float4 z4; z4.x = z4.y = z4.z = z4.w = 0.f;
#pragma unroll
    for (int t = 0; t < 4; ++t)
        *(float4*)(topk + base + (size_t)(((t << 6) + lane) << 2)) = z4;

    const uint2* wl = wlist + (size_t)row * 16;
    const float* vb = Vg + (size_t)bh * (N_ * HD_);
    float pacc = 0.f;
#pragma unroll
    for (int t = 0; t < 16; ++t) {
        uint2 e = wl[t];
        pacc = fmaf(__uint_as_float(e.y), vb[((size_t)e.x << 6) + lane], pacc);
    }
    aout[((size_t)(b * N_ + n)) * C_ + (h << 6) + lane] = pacc;

    asm volatile("s_waitcnt vmcnt(0)" ::: "memory");
    if (lane < 16) {
        uint2 e = wl[lane];
        topk[base + e.x] = __uint_as_float(e.y);
    }
}

extern "C" void kernel_launch(void* const* d_in, const int* in_sizes, int n_in,
                              void* d_out, int out_size, void* d_ws, size_t ws_size,
                              hipStream_t stream)
{
    (void)in_sizes; (void)n_in; (void)out_size; (void)ws_size;
    const float* query = (const float*)d_in[0];
    const float* win   = (const float*)d_in[1];
    const float* bin   = (const float*)d_in[2];
    const float* wout  = (const float*)d_in[3];
    const float* bout  = (const float*)d_in[4];

    float* ws = (float*)d_ws;
    float* Qp   = ws;                                   // [BH][N][64]
    float* Ktg  = Qp  + (size_t)BH_ * N_ * HD_;         // [BH][64][N]  (K transposed)
    float* Vp   = Ktg + (size_t)BH_ * N_ * HD_;         // [BH][N][64]
    float* aout = Vp  + (size_t)BH_ * N_ * HD_;         // [8192][768]
    uint2* wlist = (uint2*)(aout + (size_t)B_ * N_ * C_); // [BH*N][16]

    float* outp = (float*)d_out;
    float* topk = outp + (size_t)B_ * N_ * C_;

    gemm_k<8192, 1536, 768, 1><<<128 * 12, 256, 0, stream>>>(query, win, bin, Qp);  // Q + K^T fp32 (64x128 tile)
    gemm_bf_k<8192, 768, 2><<<64 * 6, 256, 0, stream>>>(query, win + (size_t)1536 * 768,
                                                        bin + 1536, Vp);            // V bf16 MFMA
    attn_k<<<BH_ * 128, 256, 0, stream>>>(Qp, Ktg, wlist);
    pv_scatter_k<<<BH_ * N_ / 4, 256, 0, stream>>>(wlist, Vp, topk, aout);
    gemm_bf_k<8192, 768, 0><<<64 * 6, 256, 0, stream>>>(aout, wout, bout, outp);    // out-proj bf16 MFMA
}

// Round 18
// 783.081 us; speedup vs baseline: 1.3625x; 1.3625x over previous
//
#include <hip/hip_runtime.h>
#include <float.h>
#include <math.h>

#define B_ 8
#define N_ 1024
#define C_ 768
#define H_ 12
#define HD_ 64
#define BH_ (B_*H_)

typedef __attribute__((ext_vector_type(8))) short bf16x8;
typedef __attribute__((ext_vector_type(4))) float f32x4;

// ordered-uint pack: bigger key = (bigger value) or (equal value, smaller idx)
__device__ __forceinline__ unsigned long long makekey(float v, int idx) {
    unsigned int b = __float_as_uint(v);
    unsigned int o = (b & 0x80000000u) ? ~b : (b | 0x80000000u);
    return ((unsigned long long)o << 32) | (unsigned int)(1023 - idx);
}
__device__ __forceinline__ float keyval(unsigned long long k) {
    unsigned int ordv = (unsigned int)(k >> 32);
    unsigned int fb = (ordv & 0x80000000u) ? (ordv & 0x7FFFFFFFu) : ~ordv;
    return __uint_as_float(fb);
}
// RNE f32 -> bf16 (no NaN inputs here)
__device__ __forceinline__ unsigned short f2bf(float f) {
    unsigned int u = __float_as_uint(f);
    return (unsigned short)((u + 0x7FFFu + ((u >> 16) & 1u)) >> 16);
}

// ---------------- fp32 GEMM (Q,K selection path): C = A * W^T + bias ----------------
// r16-proven: tile 128x128, LDS double-buffered, XCD-swizzled, sequential K chain.
// MODE 1: o/768==0 -> Q row-major [bh][n][64]; ==1 -> K TRANSPOSED [bh][d][n].
template<int MM, int NN, int KD, int MODE>
__global__ void __launch_bounds__(256)
gemm_k(const float* __restrict__ A, const float* __restrict__ W,
       const float* __restrict__ bias, float* __restrict__ out)
{
    __shared__ float As[2][16][132];
    __shared__ float Bs[2][16][132];
    const int tid = threadIdx.x;
    constexpr int NBLK = NN / 128;
    constexpr int NWG = (MM / 128) * NBLK;          // multiple of 8
    const int eff = (blockIdx.x & 7) * (NWG / 8) + (blockIdx.x >> 3);  // bijective XCD swizzle
    const int bm = eff / NBLK;
    const int bn = eff % NBLK;
    const int m0 = bm * 128, n0 = bn * 128;
    const int ty = tid >> 4, tx = tid & 15;
    const int ar = tid >> 2;           // 0..63
    const int ac = (tid & 3) << 2;     // 0,4,8,12

    float acc[8][8];
#pragma unroll
    for (int i = 0; i < 8; ++i)
#pragma unroll
        for (int j = 0; j < 8; ++j) acc[i][j] = 0.f;

    const float* A0 = A + (size_t)(m0 + ar) * KD + ac;
    const float* A1 = A + (size_t)(m0 + ar + 64) * KD + ac;
    const float* W0 = W + (size_t)(n0 + ar) * KD + ac;
    const float* W1 = W + (size_t)(n0 + ar + 64) * KD + ac;

    float4 pa0 = *(const float4*)A0;
    float4 pa1 = *(const float4*)A1;
    float4 pb0 = *(const float4*)W0;
    float4 pb1 = *(const float4*)W1;

    As[0][ac+0][ar]    = pa0.x; As[0][ac+1][ar]    = pa0.y; As[0][ac+2][ar]    = pa0.z; As[0][ac+3][ar]    = pa0.w;
    As[0][ac+0][ar+64] = pa1.x; As[0][ac+1][ar+64] = pa1.y; As[0][ac+2][ar+64] = pa1.z; As[0][ac+3][ar+64] = pa1.w;
    Bs[0][ac+0][ar]    = pb0.x; Bs[0][ac+1][ar]    = pb0.y; Bs[0][ac+2][ar]    = pb0.z; Bs[0][ac+3][ar]    = pb0.w;
    Bs[0][ac+0][ar+64] = pb1.x; Bs[0][ac+1][ar+64] = pb1.y; Bs[0][ac+2][ar+64] = pb1.z; Bs[0][ac+3][ar+64] = pb1.w;
    __syncthreads();

    int cur = 0;
    for (int k0 = 0; k0 < KD; k0 += 16) {
        const bool more = (k0 + 16 < KD);
        if (more) {
            pa0 = *(const float4*)(A0 + k0 + 16);
            pa1 = *(const float4*)(A1 + k0 + 16);
            pb0 = *(const float4*)(W0 + k0 + 16);
            pb1 = *(const float4*)(W1 + k0 + 16);
        }
        const float (*Ac)[132] = As[cur];
        const float (*Bc)[132] = Bs[cur];
#pragma unroll
        for (int kk = 0; kk < 16; ++kk) {
            float4 a0v = *(const float4*)&Ac[kk][ty * 4];
            float4 a1v = *(const float4*)&Ac[kk][64 + ty * 4];
            float4 b0v = *(const float4*)&Bc[kk][tx * 4];
            float4 b1v = *(const float4*)&Bc[kk][64 + tx * 4];
            float av[8] = {a0v.x,a0v.y,a0v.z,a0v.w, a1v.x,a1v.y,a1v.z,a1v.w};
            float bv[8] = {b0v.x,b0v.y,b0v.z,b0v.w, b1v.x,b1v.y,b1v.z,b1v.w};
#pragma unroll
            for (int i = 0; i < 8; ++i)
#pragma unroll
                for (int j = 0; j < 8; ++j)
                    acc[i][j] = fmaf(av[i], bv[j], acc[i][j]);
        }
        if (more) {
            const int nxt = cur ^ 1;
            As[nxt][ac+0][ar]    = pa0.x; As[nxt][ac+1][ar]    = pa0.y; As[nxt][ac+2][ar]    = pa0.z; As[nxt][ac+3][ar]    = pa0.w;
            As[nxt][ac+0][ar+64] = pa1.x; As[nxt][ac+1][ar+64] = pa1.y; As[nxt][ac+2][ar+64] = pa1.z; As[nxt][ac+3][ar+64] = pa1.w;
            Bs[nxt][ac+0][ar]    = pb0.x; Bs[nxt][ac+1][ar]    = pb0.y; Bs[nxt][ac+2][ar]    = pb0.z; Bs[nxt][ac+3][ar]    = pb0.w;
            Bs[nxt][ac+0][ar+64] = pb1.x; Bs[nxt][ac+1][ar+64] = pb1.y; Bs[nxt][ac+2][ar+64] = pb1.z; Bs[nxt][ac+3][ar+64] = pb1.w;
            __syncthreads();
            cur = nxt;
        }
    }

#pragma unroll
    for (int gi = 0; gi < 2; ++gi)
#pragma unroll
    for (int i = 0; i < 4; ++i) {
        const int m = m0 + gi * 64 + ty * 4 + i;
        const int ai = gi * 4 + i;
#pragma unroll
        for (int gj = 0; gj < 2; ++gj) {
            const int o = n0 + gj * 64 + tx * 4;
            const int aj = gj * 4;
            float4 bv4 = *(const float4*)(bias + o);
            float4 v;
            v.x = acc[ai][aj+0] + bv4.x;
            v.y = acc[ai][aj+1] + bv4.y;
            v.z = acc[ai][aj+2] + bv4.z;
            v.w = acc[ai][aj+3] + bv4.w;
            if (MODE == 0) {
                *(float4*)(out + (size_t)m * NN + o) = v;
            } else {
                const int which = o / 768;           // 0=Q, 1=K
                const int r = o - which * 768;
                const int hh = r >> 6;
                const int dd = r & 63;
                const int bh = (m >> 10) * H_ + hh;
                const int nn = m & 1023;
                if (which == 1) {
                    // K TRANSPOSED: [bh][d][n]
                    float* dst = out + (size_t)BH_ * N_ * HD_
                               + ((size_t)bh * HD_ + dd) * N_ + nn;
                    dst[0]      = v.x;
                    dst[N_]     = v.y;
                    dst[2 * N_] = v.z;
                    dst[3 * N_] = v.w;
                } else {
                    float* dst = out + ((size_t)bh * N_ + nn) * HD_ + dd;
                    *(float4*)dst = v;
                }
            }
        }
    }
}

// ---------------- bf16 MFMA GEMM (value path): C = A * W^T + bias ----------------
// r16-proven: tile 128x128, BK=32, 4 waves, MFMA 16x16x32.
template<int MM, int NN, int MODE>
__global__ void __launch_bounds__(256)
gemm_bf_k(const float* __restrict__ A, const float* __restrict__ W,
          const float* __restrict__ bias, float* __restrict__ out)
{
    __shared__ unsigned short Asb[128][40];
    __shared__ unsigned short Bsb[128][40];
    const int tid = threadIdx.x;
    constexpr int NBLK = NN / 128;
    constexpr int NWG = (MM / 128) * NBLK;
    const int eff = (blockIdx.x & 7) * (NWG / 8) + (blockIdx.x >> 3);
    const int bm = eff / NBLK;
    const int bn = eff % NBLK;
    const int m0 = bm * 128, n0 = bn * 128;
    const int lane = tid & 63;
    const int w = tid >> 6;
    const int wm = (w >> 1) << 6;
    const int wn = (w & 1) << 6;

    f32x4 acc[4][4];
#pragma unroll
    for (int i = 0; i < 4; ++i)
#pragma unroll
        for (int j = 0; j < 4; ++j) acc[i][j] = (f32x4){0.f, 0.f, 0.f, 0.f};

    const int srow = tid >> 1;
    const int sks  = (tid & 1) << 4;
    const float* ga = A + (size_t)(m0 + srow) * 768 + sks;
    const float* gw = W + (size_t)(n0 + srow) * 768 + sks;

    for (int k0 = 0; k0 < 768; k0 += 32) {
        __syncthreads();
        {
            float4 f0 = *(const float4*)(ga + k0 + 0);
            float4 f1 = *(const float4*)(ga + k0 + 4);
            float4 f2 = *(const float4*)(ga + k0 + 8);
            float4 f3 = *(const float4*)(ga + k0 + 12);
            unsigned short* d = &Asb[srow][sks];
            d[0]=f2bf(f0.x);  d[1]=f2bf(f0.y);  d[2]=f2bf(f0.z);  d[3]=f2bf(f0.w);
            d[4]=f2bf(f1.x);  d[5]=f2bf(f1.y);  d[6]=f2bf(f1.z);  d[7]=f2bf(f1.w);
            d[8]=f2bf(f2.x);  d[9]=f2bf(f2.y);  d[10]=f2bf(f2.z); d[11]=f2bf(f2.w);
            d[12]=f2bf(f3.x); d[13]=f2bf(f3.y); d[14]=f2bf(f3.z); d[15]=f2bf(f3.w);
            f0 = *(const float4*)(gw + k0 + 0);
            f1 = *(const float4*)(gw + k0 + 4);
            f2 = *(const float4*)(gw + k0 + 8);
            f3 = *(const float4*)(gw + k0 + 12);
            unsigned short* e = &Bsb[srow][sks];
            e[0]=f2bf(f0.x);  e[1]=f2bf(f0.y);  e[2]=f2bf(f0.z);  e[3]=f2bf(f0.w);
            e[4]=f2bf(f1.x);  e[5]=f2bf(f1.y);  e[6]=f2bf(f1.z);  e[7]=f2bf(f1.w);
            e[8]=f2bf(f2.x);  e[9]=f2bf(f2.y);  e[10]=f2bf(f2.z); e[11]=f2bf(f2.w);
            e[12]=f2bf(f3.x); e[13]=f2bf(f3.y); e[14]=f2bf(f3.z); e[15]=f2bf(f3.w);
        }
        __syncthreads();

        bf16x8 af[4], bf[4];
        const int fr = lane & 15;
        const int fk = (lane >> 4) << 3;
#pragma unroll
        for (int fi = 0; fi < 4; ++fi)
            af[fi] = *(const bf16x8*)&Asb[wm + (fi << 4) + fr][fk];
#pragma unroll
        for (int fj = 0; fj < 4; ++fj)
            bf[fj] = *(const bf16x8*)&Bsb[wn + (fj << 4) + fr][fk];
#pragma unroll
        for (int fi = 0; fi < 4; ++fi)
#pragma unroll
            for (int fj = 0; fj < 4; ++fj)
                acc[fi][fj] = __builtin_amdgcn_mfma_f32_16x16x32_bf16(af[fi], bf[fj], acc[fi][fj], 0, 0, 0);
    }

    const int cr = (lane >> 4) << 2;
    const int cc = lane & 15;
#pragma unroll
    for (int fj = 0; fj < 4; ++fj) {
        const int col = n0 + wn + (fj << 4) + cc;
        const float bb = bias[col];
#pragma unroll
        for (int fi = 0; fi < 4; ++fi) {
#pragma unroll
            for (int j = 0; j < 4; ++j) {
                const int row = m0 + wm + (fi << 4) + cr + j;
                const float val = acc[fi][fj][j] + bb;
                if (MODE == 0) {
                    out[(size_t)row * NN + col] = val;
                } else {
                    const int hh = col >> 6;
                    const int dd = col & 63;
                    const int bh = (row >> 10) * H_ + hh;
                    const int nn = row & 1023;
                    out[((size_t)bh * N_ + nn) * HD_ + dd] = val;
                }
            }
        }
    }
}

// ------- fused scores + top-16 (tiered rank-count, u64 keys) -> compact winner list -------
// grid: BH_*128 = 12288 blocks (XCD-swizzled), 256 threads (4 waves). Each block: 8 q-rows.
// Wave w = col-group (cols w*256..+255); thread tile 8 rows x 4 cols (R_w=8).
__global__ void __launch_bounds__(256, 5)
attn_k(const float* __restrict__ Qg, const float* __restrict__ Ktg,
       uint2* __restrict__ wlist)
{
    __shared__ float Qs[64][8];                     // 2 KB   [d][q]
    __shared__ float qm[8][64];                     // 2 KB   quad maxes per row (4 cgs x 16)
    __shared__ unsigned long long kbuf[8][384];     // 24 KB  survivor keys (4 segs x 96 per row)
    __shared__ int cnt[8][4];                       // 128 B
    __shared__ uint2 w16s[8][16];                   // 1 KB   winners by rank (idx, wgt-bits)

    const int tid = threadIdx.x;
    const int lane = tid & 63;
    const int w = tid >> 6;                         // 0..3 col-group
    const int eff = (blockIdx.x & 7) * 1536 + (blockIdx.x >> 3);
    const int bh = eff >> 7;
    const int qt = eff & 127;
    const int q0 = qt << 3;
    const size_t kvbase = (size_t)bh * (N_ * HD_);

    if (tid < 128) {   // stage Q transposed: Qs[d][q]
        int q = tid >> 4;                           // 0..7
        int d4 = (tid & 15) << 2;
        float4 v = *(const float4*)(Qg + kvbase + (size_t)(q0 + q) * HD_ + d4);
        Qs[d4+0][q] = v.x; Qs[d4+1][q] = v.y; Qs[d4+2][q] = v.z; Qs[d4+3][q] = v.w;
    }
    __syncthreads();

    float acc[8][4];
#pragma unroll
    for (int r = 0; r < 8; ++r)
#pragma unroll
        for (int u = 0; u < 4; ++u) acc[r][u] = 0.f;

    const int jb = (w << 8) + (lane << 2);
    const float* kcol = Ktg + kvbase + jb;          // K^T [d][j], + d*1024

    // sequential d = 0..63 in-order fp32 FMA accumulation (np-matching)
#pragma unroll 8
    for (int d = 0; d < 64; ++d) {
        float4 kvv = *(const float4*)(kcol + (d << 10));
        float4 qa = *(const float4*)&Qs[d][0];
        float4 qb = *(const float4*)&Qs[d][4];
        float qv[8] = {qa.x, qa.y, qa.z, qa.w, qb.x, qb.y, qb.z, qb.w};
#pragma unroll
        for (int r = 0; r < 8; ++r) {
            acc[r][0] = fmaf(qv[r], kvv.x, acc[r][0]);
            acc[r][1] = fmaf(qv[r], kvv.y, acc[r][1]);
            acc[r][2] = fmaf(qv[r], kvv.z, acc[r][2]);
            acc[r][3] = fmaf(qv[r], kvv.w, acc[r][3]);
        }
    }

    // scale (exact pow2 -> ordering-safe)
#pragma unroll
    for (int r = 0; r < 8; ++r)
#pragma unroll
        for (int u = 0; u < 4; ++u) acc[r][u] *= 0.125f;

    // (a) per-row quad maxes (quad of 4 lanes = 16 cols)
#pragma unroll
    for (int rr = 0; rr < 8; ++rr) {
        float lm = fmaxf(fmaxf(acc[rr][0], acc[rr][1]), fmaxf(acc[rr][2], acc[rr][3]));
        lm = fmaxf(lm, __shfl_xor(lm, 1));
        lm = fmaxf(lm, __shfl_xor(lm, 2));
        if ((lane & 3) == 0) qm[rr][(w << 4) + (lane >> 2)] = lm;
    }
    __syncthreads();

    // (c) threshold T = min of 16 disjoint supergroup-maxes; compact survivors (cap 96/seg)
#pragma unroll
    for (int rr = 0; rr < 8; ++rr) {
        const int g = lane & 15;
        float sg = fmaxf(fmaxf(qm[rr][g], qm[rr][16 + g]),
                         fmaxf(qm[rr][32 + g], qm[rr][48 + g]));
        sg = fminf(sg, __shfl_xor(sg, 1));
        sg = fminf(sg, __shfl_xor(sg, 2));
        sg = fminf(sg, __shfl_xor(sg, 4));
        sg = fminf(sg, __shfl_xor(sg, 8));
        const float T = sg;
        int base = 0;
        unsigned long long lowmask = (lane == 0) ? 0ull : ((1ull << lane) - 1ull);
#pragma unroll
        for (int u = 0; u < 4; ++u) {
            bool f = acc[rr][u] >= T;
            unsigned long long m = __ballot(f);
            int pos = base + __popcll(m & lowmask);
            if (f && pos < 96) kbuf[rr][w * 96 + pos] = makekey(acc[rr][u], jb + u);
            base += __popcll(m);
        }
        if (lane == 0) cnt[rr][w] = base < 96 ? base : 96;
    }
    __syncthreads();

    // (e) selection: wave w owns rows 2w, 2w+1; tiered rank-count -> wlist
#pragma unroll 1
    for (int rr2 = 0; rr2 < 2; ++rr2) {
        const int r = (w << 1) | rr2;
        const int c0n = cnt[r][0], c1n = cnt[r][1], c2n = cnt[r][2], c3n = cnt[r][3];
        const int pfx1 = c0n, pfx2 = c0n + c1n, pfx3 = c0n + c1n + c2n;
        const int Ctot = pfx3 + c3n;             // 16..384

        auto mapk = [&](int p) -> unsigned long long {
            if (p >= Ctot) return 0ull;
            int wseg, pos;
            if (p < pfx1)      { wseg = 0; pos = p; }
            else if (p < pfx2) { wseg = 1; pos = p - pfx1; }
            else if (p < pfx3) { wseg = 2; pos = p - pfx2; }
            else               { wseg = 3; pos = p - pfx3; }
            return kbuf[r][wseg * 96 + pos];
        };

        if (Ctot <= 128) {
            unsigned long long kk0 = mapk(lane);
            unsigned long long kk1 = mapk(lane + 64);
            int n0 = 0, n1 = 0;
#pragma unroll 1
            for (int seg = 0; seg < 4; ++seg) {
                const int cn = cnt[r][seg];
                const unsigned long long* sp = &kbuf[r][seg * 96];
#pragma unroll 4
                for (int p = 0; p < cn; ++p) {
                    unsigned long long kp = sp[p];   // broadcast read
                    n0 += (kp > kk0); n1 += (kp > kk1);
                }
            }
            float v0 = keyval(kk0), v1 = keyval(kk1);
            float mc = -FLT_MAX;
            if (n0 == 0) mc = v0;
            if (n1 == 0) mc = v1;
#pragma unroll
            for (int off = 1; off < 64; off <<= 1) mc = fmaxf(mc, __shfl_xor(mc, off));
            float e0 = (n0 < 16) ? expf(v0 - mc) : 0.f;
            float e1 = (n1 < 16) ? expf(v1 - mc) : 0.f;
            float es = e0 + e1;
#pragma unroll
            for (int off = 1; off < 64; off <<= 1) es += __shfl_xor(es, off);
            if (n0 < 16) w16s[r][n0] = make_uint2(1023u - (unsigned)(kk0 & 0xFFFFFFFFull), __float_as_uint(e0 / es));
            if (n1 < 16) w16s[r][n1] = make_uint2(1023u - (unsigned)(kk1 & 0xFFFFFFFFull), __float_as_uint(e1 / es));
        } else {
            unsigned long long kk0 = mapk(lane);
            unsigned long long kk1 = mapk(lane + 64);
            unsigned long long kk2 = mapk(lane + 128);
            unsigned long long kk3 = mapk(lane + 192);
            unsigned long long kk4 = mapk(lane + 256);
            unsigned long long kk5 = mapk(lane + 320);
            int n0 = 0, n1 = 0, n2 = 0, n3 = 0, n4 = 0, n5 = 0;
#pragma unroll 1
            for (int seg = 0; seg < 4; ++seg) {
                const int cn = cnt[r][seg];
                const unsigned long long* sp = &kbuf[r][seg * 96];
#pragma unroll 2
                for (int p = 0; p < cn; ++p) {
                    unsigned long long kp = sp[p];
                    n0 += (kp > kk0); n1 += (kp > kk1); n2 += (kp > kk2);
                    n3 += (kp > kk3); n4 += (kp > kk4); n5 += (kp > kk5);
                }
            }
            float v0 = keyval(kk0), v1 = keyval(kk1), v2 = keyval(kk2);
            float v3 = keyval(kk3), v4 = keyval(kk4), v5 = keyval(kk5);
            float mc = -FLT_MAX;
            if (n0 == 0) mc = v0;
            if (n1 == 0) mc = v1;
            if (n2 == 0) mc = v2;
            if (n3 == 0) mc = v3;
            if (n4 == 0) mc = v4;
            if (n5 == 0) mc = v5;
#pragma unroll
            for (int off = 1; off < 64; off <<= 1) mc = fmaxf(mc, __shfl_xor(mc, off));
            float e0 = (n0 < 16) ? expf(v0 - mc) : 0.f;
            float e1 = (n1 < 16) ? expf(v1 - mc) : 0.f;
            float e2 = (n2 < 16) ? expf(v2 - mc) : 0.f;
            float e3 = (n3 < 16) ? expf(v3 - mc) : 0.f;
            float e4 = (n4 < 16) ? expf(v4 - mc) : 0.f;
            float e5 = (n5 < 16) ? expf(v5 - mc) : 0.f;
            float es = e0 + e1 + e2 + e3 + e4 + e5;
#pragma unroll
            for (int off = 1; off < 64; off <<= 1) es += __shfl_xor(es, off);
            if (n0 < 16) w16s[r][n0] = make_uint2(1023u - (unsigned)(kk0 & 0xFFFFFFFFull), __float_as_uint(e0 / es));
            if (n1 < 16) w16s[r][n1] = make_uint2(1023u - (unsigned)(kk1 & 0xFFFFFFFFull), __float_as_uint(e1 / es));
            if (n2 < 16) w16s[r][n2] = make_uint2(1023u - (unsigned)(kk2 & 0xFFFFFFFFull), __float_as_uint(e2 / es));
            if (n3 < 16) w16s[r][n3] = make_uint2(1023u - (unsigned)(kk3 & 0xFFFFFFFFull), __float_as_uint(e3 / es));
            if (n4 < 16) w16s[r][n4] = make_uint2(1023u - (unsigned)(kk4 & 0xFFFFFFFFull), __float_as_uint(e4 / es));
            if (n5 < 16) w16s[r][n5] = make_uint2(1023u - (unsigned)(kk5 & 0xFFFFFFFFull), __float_as_uint(e5 / es));
        }
        asm volatile("s_waitcnt lgkmcnt(0)" ::: "memory");   // in-wave LDS write->read ordering
        __builtin_amdgcn_sched_barrier(0);

        if (lane < 16)
            wlist[((size_t)bh * N_ + q0 + r) * 16 + lane] = w16s[r][lane];
    }
}

// ------- PV + aout + topk zero-fill/scatter (barrier-free, pure throughput) -------
__global__ void __launch_bounds__(256)
pv_scatter_k(const uint2* __restrict__ wlist, const float* __restrict__ Vg,
             float* __restrict__ topk, float* __restrict__ aout)
{
    const int tid = threadIdx.x;
    const int lane = tid & 63;
    const int row = (blockIdx.x << 2) + (tid >> 6);
    const size_t base = (size_t)row << 10;
    const int bh = row >> 10;
    const int n = row & 1023;
    const int b = bh / H_;
    const int h = bh - b * H_;

    float4 z4; z4.x = z4.y = z4.z = z4.w = 0.f;
#pragma unroll
    for (int t = 0; t < 4; ++t)
        *(float4*)(topk + base + (size_t)(((t << 6) + lane) << 2)) = z4;

    const uint2* wl = wlist + (size_t)row * 16;
    const float* vb = Vg + (size_t)bh * (N_ * HD_);
    float pacc = 0.f;
#pragma unroll
    for (int t = 0; t < 16; ++t) {
        uint2 e = wl[t];
        pacc = fmaf(__uint_as_float(e.y), vb[((size_t)e.x << 6) + lane], pacc);
    }
    aout[((size_t)(b * N_ + n)) * C_ + (h << 6) + lane] = pacc;

    asm volatile("s_waitcnt vmcnt(0)" ::: "memory");
    if (lane < 16) {
        uint2 e = wl[lane];
        topk[base + e.x] = __uint_as_float(e.y);
    }
}

extern "C" void kernel_launch(void* const* d_in, const int* in_sizes, int n_in,
                              void* d_out, int out_size, void* d_ws, size_t ws_size,
                              hipStream_t stream)
{
    (void)in_sizes; (void)n_in; (void)out_size; (void)ws_size;
    const float* query = (const float*)d_in[0];
    const float* win   = (const float*)d_in[1];
    const float* bin   = (const float*)d_in[2];
    const float* wout  = (const float*)d_in[3];
    const float* bout  = (const float*)d_in[4];

    float* ws = (float*)d_ws;
    float* Qp   = ws;                                   // [BH][N][64]
    float* Ktg  = Qp  + (size_t)BH_ * N_ * HD_;         // [BH][64][N]  (K transposed)
    float* Vp   = Ktg + (size_t)BH_ * N_ * HD_;         // [BH][N][64]
    float* aout = Vp  + (size_t)BH_ * N_ * HD_;         // [8192][768]
    uint2* wlist = (uint2*)(aout + (size_t)B_ * N_ * C_); // [BH*N][16]

    float* outp = (float*)d_out;
    float* topk = outp + (size_t)B_ * N_ * C_;

    gemm_k<8192, 1536, 768, 1><<<64 * 12, 256, 0, stream>>>(query, win, bin, Qp);   // Q + K^T fp32 (128x128 tile)
    gemm_bf_k<8192, 768, 2><<<64 * 6, 256, 0, stream>>>(query, win + (size_t)1536 * 768,
                                                        bin + 1536, Vp);            // V bf16 MFMA
    attn_k<<<BH_ * 128, 256, 0, stream>>>(Qp, Ktg, wlist);
    pv_scatter_k<<<BH_ * N_ / 4, 256, 0, stream>>>(wlist, Vp, topk, aout);
    gemm_bf_k<8192, 768, 0><<<64 * 6, 256, 0, stream>>>(aout, wout, bout, outp);    // out-proj bf16 MFMA
}

// Round 19
// 762.795 us; speedup vs baseline: 1.3987x; 1.0266x over previous
//
#include <hip/hip_runtime.h>
#include <float.h>
#include <math.h>

#define B_ 8
#define N_ 1024
#define C_ 768
#define H_ 12
#define HD_ 64
#define BH_ (B_*H_)

typedef __attribute__((ext_vector_type(8))) short bf16x8;
typedef __attribute__((ext_vector_type(4))) float f32x4;

// ordered-uint pack: bigger key = (bigger value) or (equal value, smaller idx)
__device__ __forceinline__ unsigned long long makekey(float v, int idx) {
    unsigned int b = __float_as_uint(v);
    unsigned int o = (b & 0x80000000u) ? ~b : (b | 0x80000000u);
    return ((unsigned long long)o << 32) | (unsigned int)(1023 - idx);
}
__device__ __forceinline__ float keyval(unsigned long long k) {
    unsigned int ordv = (unsigned int)(k >> 32);
    unsigned int fb = (ordv & 0x80000000u) ? (ordv & 0x7FFFFFFFu) : ~ordv;
    return __uint_as_float(fb);
}
// RNE f32 -> bf16 (no NaN inputs here)
__device__ __forceinline__ unsigned short f2bf(float f) {
    unsigned int u = __float_as_uint(f);
    return (unsigned short)((u + 0x7FFFu + ((u >> 16) & 1u)) >> 16);
}

// ---------------- fp32 GEMM (Q,K selection path): C = A * W^T + bias ----------------
// r16-proven: tile 128x128, LDS double-buffered, XCD-swizzled, sequential K chain.
// MODE 1: o/768==0 -> Q row-major [bh][n][64]; ==1 -> K TRANSPOSED [bh][d][n].
template<int MM, int NN, int KD, int MODE>
__global__ void __launch_bounds__(256)
gemm_k(const float* __restrict__ A, const float* __restrict__ W,
       const float* __restrict__ bias, float* __restrict__ out)
{
    __shared__ float As[2][16][132];
    __shared__ float Bs[2][16][132];
    const int tid = threadIdx.x;
    constexpr int NBLK = NN / 128;
    constexpr int NWG = (MM / 128) * NBLK;          // multiple of 8
    const int eff = (blockIdx.x & 7) * (NWG / 8) + (blockIdx.x >> 3);  // bijective XCD swizzle
    const int bm = eff / NBLK;
    const int bn = eff % NBLK;
    const int m0 = bm * 128, n0 = bn * 128;
    const int ty = tid >> 4, tx = tid & 15;
    const int ar = tid >> 2;           // 0..63
    const int ac = (tid & 3) << 2;     // 0,4,8,12

    float acc[8][8];
#pragma unroll
    for (int i = 0; i < 8; ++i)
#pragma unroll
        for (int j = 0; j < 8; ++j) acc[i][j] = 0.f;

    const float* A0 = A + (size_t)(m0 + ar) * KD + ac;
    const float* A1 = A + (size_t)(m0 + ar + 64) * KD + ac;
    const float* W0 = W + (size_t)(n0 + ar) * KD + ac;
    const float* W1 = W + (size_t)(n0 + ar + 64) * KD + ac;

    float4 pa0 = *(const float4*)A0;
    float4 pa1 = *(const float4*)A1;
    float4 pb0 = *(const float4*)W0;
    float4 pb1 = *(const float4*)W1;

    As[0][ac+0][ar]    = pa0.x; As[0][ac+1][ar]    = pa0.y; As[0][ac+2][ar]    = pa0.z; As[0][ac+3][ar]    = pa0.w;
    As[0][ac+0][ar+64] = pa1.x; As[0][ac+1][ar+64] = pa1.y; As[0][ac+2][ar+64] = pa1.z; As[0][ac+3][ar+64] = pa1.w;
    Bs[0][ac+0][ar]    = pb0.x; Bs[0][ac+1][ar]    = pb0.y; Bs[0][ac+2][ar]    = pb0.z; Bs[0][ac+3][ar]    = pb0.w;
    Bs[0][ac+0][ar+64] = pb1.x; Bs[0][ac+1][ar+64] = pb1.y; Bs[0][ac+2][ar+64] = pb1.z; Bs[0][ac+3][ar+64] = pb1.w;
    __syncthreads();

    int cur = 0;
    for (int k0 = 0; k0 < KD; k0 += 16) {
        const bool more = (k0 + 16 < KD);
        if (more) {
            pa0 = *(const float4*)(A0 + k0 + 16);
            pa1 = *(const float4*)(A1 + k0 + 16);
            pb0 = *(const float4*)(W0 + k0 + 16);
            pb1 = *(const float4*)(W1 + k0 + 16);
        }
        const float (*Ac)[132] = As[cur];
        const float (*Bc)[132] = Bs[cur];
#pragma unroll
        for (int kk = 0; kk < 16; ++kk) {
            float4 a0v = *(const float4*)&Ac[kk][ty * 4];
            float4 a1v = *(const float4*)&Ac[kk][64 + ty * 4];
            float4 b0v = *(const float4*)&Bc[kk][tx * 4];
            float4 b1v = *(const float4*)&Bc[kk][64 + tx * 4];
            float av[8] = {a0v.x,a0v.y,a0v.z,a0v.w, a1v.x,a1v.y,a1v.z,a1v.w};
            float bv[8] = {b0v.x,b0v.y,b0v.z,b0v.w, b1v.x,b1v.y,b1v.z,b1v.w};
#pragma unroll
            for (int i = 0; i < 8; ++i)
#pragma unroll
                for (int j = 0; j < 8; ++j)
                    acc[i][j] = fmaf(av[i], bv[j], acc[i][j]);
        }
        if (more) {
            const int nxt = cur ^ 1;
            As[nxt][ac+0][ar]    = pa0.x; As[nxt][ac+1][ar]    = pa0.y; As[nxt][ac+2][ar]    = pa0.z; As[nxt][ac+3][ar]    = pa0.w;
            As[nxt][ac+0][ar+64] = pa1.x; As[nxt][ac+1][ar+64] = pa1.y; As[nxt][ac+2][ar+64] = pa1.z; As[nxt][ac+3][ar+64] = pa1.w;
            Bs[nxt][ac+0][ar]    = pb0.x; Bs[nxt][ac+1][ar]    = pb0.y; Bs[nxt][ac+2][ar]    = pb0.z; Bs[nxt][ac+3][ar]    = pb0.w;
            Bs[nxt][ac+0][ar+64] = pb1.x; Bs[nxt][ac+1][ar+64] = pb1.y; Bs[nxt][ac+2][ar+64] = pb1.z; Bs[nxt][ac+3][ar+64] = pb1.w;
            __syncthreads();
            cur = nxt;
        }
    }

#pragma unroll
    for (int gi = 0; gi < 2; ++gi)
#pragma unroll
    for (int i = 0; i < 4; ++i) {
        const int m = m0 + gi * 64 + ty * 4 + i;
        const int ai = gi * 4 + i;
#pragma unroll
        for (int gj = 0; gj < 2; ++gj) {
            const int o = n0 + gj * 64 + tx * 4;
            const int aj = gj * 4;
            float4 bv4 = *(const float4*)(bias + o);
            float4 v;
            v.x = acc[ai][aj+0] + bv4.x;
            v.y = acc[ai][aj+1] + bv4.y;
            v.z = acc[ai][aj+2] + bv4.z;
            v.w = acc[ai][aj+3] + bv4.w;
            if (MODE == 0) {
                *(float4*)(out + (size_t)m * NN + o) = v;
            } else {
                const int which = o / 768;           // 0=Q, 1=K
                const int r = o - which * 768;
                const int hh = r >> 6;
                const int dd = r & 63;
                const int bh = (m >> 10) * H_ + hh;
                const int nn = m & 1023;
                if (which == 1) {
                    // K TRANSPOSED: [bh][d][n]
                    float* dst = out + (size_t)BH_ * N_ * HD_
                               + ((size_t)bh * HD_ + dd) * N_ + nn;
                    dst[0]      = v.x;
                    dst[N_]     = v.y;
                    dst[2 * N_] = v.z;
                    dst[3 * N_] = v.w;
                } else {
                    float* dst = out + ((size_t)bh * N_ + nn) * HD_ + dd;
                    *(float4*)dst = v;
                }
            }
        }
    }
}

// ---------------- bf16 MFMA GEMM (value path): C = A * W^T + bias ----------------
// r16-proven: tile 128x128, BK=32, 4 waves, MFMA 16x16x32.
template<int MM, int NN, int MODE>
__global__ void __launch_bounds__(256)
gemm_bf_k(const float* __restrict__ A, const float* __restrict__ W,
          const float* __restrict__ bias, float* __restrict__ out)
{
    __shared__ unsigned short Asb[128][40];
    __shared__ unsigned short Bsb[128][40];
    const int tid = threadIdx.x;
    constexpr int NBLK = NN / 128;
    constexpr int NWG = (MM / 128) * NBLK;
    const int eff = (blockIdx.x & 7) * (NWG / 8) + (blockIdx.x >> 3);
    const int bm = eff / NBLK;
    const int bn = eff % NBLK;
    const int m0 = bm * 128, n0 = bn * 128;
    const int lane = tid & 63;
    const int w = tid >> 6;
    const int wm = (w >> 1) << 6;
    const int wn = (w & 1) << 6;

    f32x4 acc[4][4];
#pragma unroll
    for (int i = 0; i < 4; ++i)
#pragma unroll
        for (int j = 0; j < 4; ++j) acc[i][j] = (f32x4){0.f, 0.f, 0.f, 0.f};

    const int srow = tid >> 1;
    const int sks  = (tid & 1) << 4;
    const float* ga = A + (size_t)(m0 + srow) * 768 + sks;
    const float* gw = W + (size_t)(n0 + srow) * 768 + sks;

    for (int k0 = 0; k0 < 768; k0 += 32) {
        __syncthreads();
        {
            float4 f0 = *(const float4*)(ga + k0 + 0);
            float4 f1 = *(const float4*)(ga + k0 + 4);
            float4 f2 = *(const float4*)(ga + k0 + 8);
            float4 f3 = *(const float4*)(ga + k0 + 12);
            unsigned short* d = &Asb[srow][sks];
            d[0]=f2bf(f0.x);  d[1]=f2bf(f0.y);  d[2]=f2bf(f0.z);  d[3]=f2bf(f0.w);
            d[4]=f2bf(f1.x);  d[5]=f2bf(f1.y);  d[6]=f2bf(f1.z);  d[7]=f2bf(f1.w);
            d[8]=f2bf(f2.x);  d[9]=f2bf(f2.y);  d[10]=f2bf(f2.z); d[11]=f2bf(f2.w);
            d[12]=f2bf(f3.x); d[13]=f2bf(f3.y); d[14]=f2bf(f3.z); d[15]=f2bf(f3.w);
            f0 = *(const float4*)(gw + k0 + 0);
            f1 = *(const float4*)(gw + k0 + 4);
            f2 = *(const float4*)(gw + k0 + 8);
            f3 = *(const float4*)(gw + k0 + 12);
            unsigned short* e = &Bsb[srow][sks];
            e[0]=f2bf(f0.x);  e[1]=f2bf(f0.y);  e[2]=f2bf(f0.z);  e[3]=f2bf(f0.w);
            e[4]=f2bf(f1.x);  e[5]=f2bf(f1.y);  e[6]=f2bf(f1.z);  e[7]=f2bf(f1.w);
            e[8]=f2bf(f2.x);  e[9]=f2bf(f2.y);  e[10]=f2bf(f2.z); e[11]=f2bf(f2.w);
            e[12]=f2bf(f3.x); e[13]=f2bf(f3.y); e[14]=f2bf(f3.z); e[15]=f2bf(f3.w);
        }
        __syncthreads();

        bf16x8 af[4], bf[4];
        const int fr = lane & 15;
        const int fk = (lane >> 4) << 3;
#pragma unroll
        for (int fi = 0; fi < 4; ++fi)
            af[fi] = *(const bf16x8*)&Asb[wm + (fi << 4) + fr][fk];
#pragma unroll
        for (int fj = 0; fj < 4; ++fj)
            bf[fj] = *(const bf16x8*)&Bsb[wn + (fj << 4) + fr][fk];
#pragma unroll
        for (int fi = 0; fi < 4; ++fi)
#pragma unroll
            for (int fj = 0; fj < 4; ++fj)
                acc[fi][fj] = __builtin_amdgcn_mfma_f32_16x16x32_bf16(af[fi], bf[fj], acc[fi][fj], 0, 0, 0);
    }

    const int cr = (lane >> 4) << 2;
    const int cc = lane & 15;
#pragma unroll
    for (int fj = 0; fj < 4; ++fj) {
        const int col = n0 + wn + (fj << 4) + cc;
        const float bb = bias[col];
#pragma unroll
        for (int fi = 0; fi < 4; ++fi) {
#pragma unroll
            for (int j = 0; j < 4; ++j) {
                const int row = m0 + wm + (fi << 4) + cr + j;
                const float val = acc[fi][fj][j] + bb;
                if (MODE == 0) {
                    out[(size_t)row * NN + col] = val;
                } else {
                    const int hh = col >> 6;
                    const int dd = col & 63;
                    const int bh = (row >> 10) * H_ + hh;
                    const int nn = row & 1023;
                    out[((size_t)bh * N_ + nn) * HD_ + dd] = val;
                }
            }
        }
    }
}

// ------- fused scores + top-16 (3-tier rank-count, u64 keys) -> compact winner list -------
// grid: BH_*128 = 12288 blocks (XCD-swizzled), 512 threads (8 waves). Each block: 8 q-rows.
// Wave w = (row-group w>>2, col-group w&3): 4 rows x 256 cols, thread tile 4 rows x 4 cols.
__global__ void __launch_bounds__(512, 8)
attn_k(const float* __restrict__ Qg, const float* __restrict__ Ktg,
       uint2* __restrict__ wlist)
{
    __shared__ float Qs[64][8];                     // 2 KB   [d][q]
    __shared__ float qm[8][64];                     // 2 KB   quad maxes per row
    __shared__ unsigned long long kbuf[8][384];     // 24 KB  survivor keys (4 segs x 96 per row)
    __shared__ int cnt[8][4];                       // 128 B
    __shared__ uint2 w16s[8][16];                   // 1 KB   winners by rank (idx, wgt-bits)

    const int tid = threadIdx.x;
    const int lane = tid & 63;
    const int w = tid >> 6;                         // 0..7
    const int rg = w >> 2;                          // row group: rows rg*4..+3
    const int cg = w & 3;                           // col group: cols cg*256..+255
    const int eff = (blockIdx.x & 7) * 1536 + (blockIdx.x >> 3);
    const int bh = eff >> 7;
    const int qt = eff & 127;
    const int q0 = qt << 3;
    const size_t kvbase = (size_t)bh * (N_ * HD_);

    if (tid < 128) {   // stage Q transposed: Qs[d][q]
        int q = tid >> 4;                           // 0..7
        int d4 = (tid & 15) << 2;
        float4 v = *(const float4*)(Qg + kvbase + (size_t)(q0 + q) * HD_ + d4);
        Qs[d4+0][q] = v.x; Qs[d4+1][q] = v.y; Qs[d4+2][q] = v.z; Qs[d4+3][q] = v.w;
    }
    __syncthreads();

    float acc[4][4];
#pragma unroll
    for (int r = 0; r < 4; ++r)
#pragma unroll
        for (int u = 0; u < 4; ++u) acc[r][u] = 0.f;

    const int jb = (cg << 8) + (lane << 2);
    const int r0 = rg << 2;
    const float* kcol = Ktg + kvbase + jb;          // K^T [d][j], + d*1024

    // sequential d = 0..63 in-order fp32 FMA accumulation (np-matching)
#pragma unroll 8
    for (int d = 0; d < 64; ++d) {
        float4 kvv = *(const float4*)(kcol + (d << 10));
        float4 qa = *(const float4*)&Qs[d][r0];
        float qv[4] = {qa.x, qa.y, qa.z, qa.w};
#pragma unroll
        for (int r = 0; r < 4; ++r) {
            acc[r][0] = fmaf(qv[r], kvv.x, acc[r][0]);
            acc[r][1] = fmaf(qv[r], kvv.y, acc[r][1]);
            acc[r][2] = fmaf(qv[r], kvv.z, acc[r][2]);
            acc[r][3] = fmaf(qv[r], kvv.w, acc[r][3]);
        }
    }

    // scale (exact pow2 -> ordering-safe)
#pragma unroll
    for (int r = 0; r < 4; ++r)
#pragma unroll
        for (int u = 0; u < 4; ++u) acc[r][u] *= 0.125f;

    // (a) per-row quad maxes (quad of 4 lanes = 16 cols)
#pragma unroll
    for (int rr = 0; rr < 4; ++rr) {
        float lm = fmaxf(fmaxf(acc[rr][0], acc[rr][1]), fmaxf(acc[rr][2], acc[rr][3]));
        lm = fmaxf(lm, __shfl_xor(lm, 1));
        lm = fmaxf(lm, __shfl_xor(lm, 2));
        if ((lane & 3) == 0) qm[r0 + rr][(cg << 4) + (lane >> 2)] = lm;
    }
    __syncthreads();

    // (c) threshold T = min of 16 disjoint supergroup-maxes; compact survivors (cap 96/seg)
#pragma unroll
    for (int rr = 0; rr < 4; ++rr) {
        const int r = r0 + rr;
        const int g = lane & 15;
        float sg = fmaxf(fmaxf(qm[r][g], qm[r][16 + g]),
                         fmaxf(qm[r][32 + g], qm[r][48 + g]));
        sg = fminf(sg, __shfl_xor(sg, 1));
        sg = fminf(sg, __shfl_xor(sg, 2));
        sg = fminf(sg, __shfl_xor(sg, 4));
        sg = fminf(sg, __shfl_xor(sg, 8));
        const float T = sg;
        int base = 0;
        unsigned long long lowmask = (lane == 0) ? 0ull : ((1ull << lane) - 1ull);
#pragma unroll
        for (int u = 0; u < 4; ++u) {
            bool f = acc[rr][u] >= T;
            unsigned long long m = __ballot(f);
            int pos = base + __popcll(m & lowmask);
            if (f && pos < 96) kbuf[r][cg * 96 + pos] = makekey(acc[rr][u], jb + u);
            base += __popcll(m);
        }
        if (lane == 0) cnt[r][cg] = base < 96 ? base : 96;
    }
    __syncthreads();

    // (e) selection: wave w owns row w; 3-tier rank-count -> wlist
    {
        const int r = w;
        const int c0n = cnt[r][0], c1n = cnt[r][1], c2n = cnt[r][2], c3n = cnt[r][3];
        const int pfx1 = c0n, pfx2 = c0n + c1n, pfx3 = c0n + c1n + c2n;
        const int Ctot = pfx3 + c3n;             // 16..384

        auto mapk = [&](int p) -> unsigned long long {
            if (p >= Ctot) return 0ull;
            int wseg, pos;
            if (p < pfx1)      { wseg = 0; pos = p; }
            else if (p < pfx2) { wseg = 1; pos = p - pfx1; }
            else if (p < pfx3) { wseg = 2; pos = p - pfx2; }
            else               { wseg = 3; pos = p - pfx3; }
            return kbuf[r][wseg * 96 + pos];
        };

        if (Ctot <= 64) {
            // ---- fastest path (~70% of rows): 1 slot covers the pool ----
            unsigned long long kk0 = mapk(lane);
            int n0 = 0;
#pragma unroll 1
            for (int seg = 0; seg < 4; ++seg) {
                const int cn = cnt[r][seg];
                const unsigned long long* sp = &kbuf[r][seg * 96];
#pragma unroll 4
                for (int p = 0; p < cn; ++p) {
                    unsigned long long kp = sp[p];   // broadcast read
                    n0 += (kp > kk0);
                }
            }
            float v0 = keyval(kk0);
            float mc = (n0 == 0) ? v0 : -FLT_MAX;
#pragma unroll
            for (int off = 1; off < 64; off <<= 1) mc = fmaxf(mc, __shfl_xor(mc, off));
            float e0 = (n0 < 16) ? expf(v0 - mc) : 0.f;
            float es = e0;
#pragma unroll
            for (int off = 1; off < 64; off <<= 1) es += __shfl_xor(es, off);
            if (n0 < 16) w16s[r][n0] = make_uint2(1023u - (unsigned)(kk0 & 0xFFFFFFFFull), __float_as_uint(e0 / es));
        } else if (Ctot <= 128) {
            // ---- common path: 2 slots ----
            unsigned long long kk0 = mapk(lane);
            unsigned long long kk1 = mapk(lane + 64);
            int n0 = 0, n1 = 0;
#pragma unroll 1
            for (int seg = 0; seg < 4; ++seg) {
                const int cn = cnt[r][seg];
                const unsigned long long* sp = &kbuf[r][seg * 96];
#pragma unroll 4
                for (int p = 0; p < cn; ++p) {
                    unsigned long long kp = sp[p];   // broadcast read
                    n0 += (kp > kk0); n1 += (kp > kk1);
                }
            }
            float v0 = keyval(kk0), v1 = keyval(kk1);
            float mc = -FLT_MAX;
            if (n0 == 0) mc = v0;
            if (n1 == 0) mc = v1;
#pragma unroll
            for (int off = 1; off < 64; off <<= 1) mc = fmaxf(mc, __shfl_xor(mc, off));
            float e0 = (n0 < 16) ? expf(v0 - mc) : 0.f;
            float e1 = (n1 < 16) ? expf(v1 - mc) : 0.f;
            float es = e0 + e1;
#pragma unroll
            for (int off = 1; off < 64; off <<= 1) es += __shfl_xor(es, off);
            if (n0 < 16) w16s[r][n0] = make_uint2(1023u - (unsigned)(kk0 & 0xFFFFFFFFull), __float_as_uint(e0 / es));
            if (n1 < 16) w16s[r][n1] = make_uint2(1023u - (unsigned)(kk1 & 0xFFFFFFFFull), __float_as_uint(e1 / es));
        } else {
            // ---- rare tail: 6 slots (Ctot <= 384) ----
            unsigned long long kk0 = mapk(lane);
            unsigned long long kk1 = mapk(lane + 64);
            unsigned long long kk2 = mapk(lane + 128);
            unsigned long long kk3 = mapk(lane + 192);
            unsigned long long kk4 = mapk(lane + 256);
            unsigned long long kk5 = mapk(lane + 320);
            int n0 = 0, n1 = 0, n2 = 0, n3 = 0, n4 = 0, n5 = 0;
#pragma unroll 1
            for (int seg = 0; seg < 4; ++seg) {
                const int cn = cnt[r][seg];
                const unsigned long long* sp = &kbuf[r][seg * 96];
#pragma unroll 2
                for (int p = 0; p < cn; ++p) {
                    unsigned long long kp = sp[p];
                    n0 += (kp > kk0); n1 += (kp > kk1); n2 += (kp > kk2);
                    n3 += (kp > kk3); n4 += (kp > kk4); n5 += (kp > kk5);
                }
            }
            float v0 = keyval(kk0), v1 = keyval(kk1), v2 = keyval(kk2);
            float v3 = keyval(kk3), v4 = keyval(kk4), v5 = keyval(kk5);
            float mc = -FLT_MAX;
            if (n0 == 0) mc = v0;
            if (n1 == 0) mc = v1;
            if (n2 == 0) mc = v2;
            if (n3 == 0) mc = v3;
            if (n4 == 0) mc = v4;
            if (n5 == 0) mc = v5;
#pragma unroll
            for (int off = 1; off < 64; off <<= 1) mc = fmaxf(mc, __shfl_xor(mc, off));
            float e0 = (n0 < 16) ? expf(v0 - mc) : 0.f;
            float e1 = (n1 < 16) ? expf(v1 - mc) : 0.f;
            float e2 = (n2 < 16) ? expf(v2 - mc) : 0.f;
            float e3 = (n3 < 16) ? expf(v3 - mc) : 0.f;
            float e4 = (n4 < 16) ? expf(v4 - mc) : 0.f;
            float e5 = (n5 < 16) ? expf(v5 - mc) : 0.f;
            float es = e0 + e1 + e2 + e3 + e4 + e5;
#pragma unroll
            for (int off = 1; off < 64; off <<= 1) es += __shfl_xor(es, off);
            if (n0 < 16) w16s[r][n0] = make_uint2(1023u - (unsigned)(kk0 & 0xFFFFFFFFull), __float_as_uint(e0 / es));
            if (n1 < 16) w16s[r][n1] = make_uint2(1023u - (unsigned)(kk1 & 0xFFFFFFFFull), __float_as_uint(e1 / es));
            if (n2 < 16) w16s[r][n2] = make_uint2(1023u - (unsigned)(kk2 & 0xFFFFFFFFull), __float_as_uint(e2 / es));
            if (n3 < 16) w16s[r][n3] = make_uint2(1023u - (unsigned)(kk3 & 0xFFFFFFFFull), __float_as_uint(e3 / es));
            if (n4 < 16) w16s[r][n4] = make_uint2(1023u - (unsigned)(kk4 & 0xFFFFFFFFull), __float_as_uint(e4 / es));
            if (n5 < 16) w16s[r][n5] = make_uint2(1023u - (unsigned)(kk5 & 0xFFFFFFFFull), __float_as_uint(e5 / es));
        }
        asm volatile("s_waitcnt lgkmcnt(0)" ::: "memory");   // in-wave LDS write->read ordering
        __builtin_amdgcn_sched_barrier(0);

        if (lane < 16)
            wlist[((size_t)bh * N_ + q0 + r) * 16 + lane] = w16s[r][lane];
    }
}

// ------- PV + aout + topk zero-fill/scatter (barrier-free, pure throughput) -------
__global__ void __launch_bounds__(256)
pv_scatter_k(const uint2* __restrict__ wlist, const float* __restrict__ Vg,
             float* __restrict__ topk, float* __restrict__ aout)
{
    const int tid = threadIdx.x;
    const int lane = tid & 63;
    const int row = (blockIdx.x << 2) + (tid >> 6);
    const size_t base = (size_t)row << 10;
    const int bh = row >> 10;
    const int n = row & 1023;
    const int b = bh / H_;
    const int h = bh - b * H_;

    float4 z4; z4.x = z4.y = z4.z = z4.w = 0.f;
#pragma unroll
    for (int t = 0; t < 4; ++t)
        *(float4*)(topk + base + (size_t)(((t << 6) + lane) << 2)) = z4;

    const uint2* wl = wlist + (size_t)row * 16;
    const float* vb = Vg + (size_t)bh * (N_ * HD_);
    float pacc = 0.f;
#pragma unroll
    for (int t = 0; t < 16; ++t) {
        uint2 e = wl[t];
        pacc = fmaf(__uint_as_float(e.y), vb[((size_t)e.x << 6) + lane], pacc);
    }
    aout[((size_t)(b * N_ + n)) * C_ + (h << 6) + lane] = pacc;

    asm volatile("s_waitcnt vmcnt(0)" ::: "memory");
    if (lane < 16) {
        uint2 e = wl[lane];
        topk[base + e.x] = __uint_as_float(e.y);
    }
}

extern "C" void kernel_launch(void* const* d_in, const int* in_sizes, int n_in,
                              void* d_out, int out_size, void* d_ws, size_t ws_size,
                              hipStream_t stream)
{
    (void)in_sizes; (void)n_in; (void)out_size; (void)ws_size;
    const float* query = (const float*)d_in[0];
    const float* win   = (const float*)d_in[1];
    const float* bin   = (const float*)d_in[2];
    const float* wout  = (const float*)d_in[3];
    const float* bout  = (const float*)d_in[4];

    float* ws = (float*)d_ws;
    float* Qp   = ws;                                   // [BH][N][64]
    float* Ktg  = Qp  + (size_t)BH_ * N_ * HD_;         // [BH][64][N]  (K transposed)
    float* Vp   = Ktg + (size_t)BH_ * N_ * HD_;         // [BH][N][64]
    float* aout = Vp  + (size_t)BH_ * N_ * HD_;         // [8192][768]
    uint2* wlist = (uint2*)(aout + (size_t)B_ * N_ * C_); // [BH*N][16]

    float* outp = (float*)d_out;
    float* topk = outp + (size_t)B_ * N_ * C_;

    gemm_k<8192, 1536, 768, 1><<<64 * 12, 256, 0, stream>>>(query, win, bin, Qp);   // Q + K^T fp32 (128x128 tile)
    gemm_bf_k<8192, 768, 2><<<64 * 6, 256, 0, stream>>>(query, win + (size_t)1536 * 768,
                                                        bin + 1536, Vp);            // V bf16 MFMA
    attn_k<<<BH_ * 128, 512, 0, stream>>>(Qp, Ktg, wlist);
    pv_scatter_k<<<BH_ * N_ / 4, 256, 0, stream>>>(wlist, Vp, topk, aout);
    gemm_bf_k<8192, 768, 0><<<64 * 6, 256, 0, stream>>>(aout, wout, bout, outp);    // out-proj bf16 MFMA
}